// Round 6
// baseline (548.178 us; speedup 1.0000x reference)
//
#include <hip/hip_runtime.h>
#include <hip/hip_bf16.h>
#include <math.h>

// Problem constants
#define B_   64
#define N_   256
#define DV_  2048
#define DP_  8
#define DT_  768
#define DF_  512
#define DK_  2056   // DV + DP

// Workspace layout (floats):
#define WS_WT 0        // wT[DF][B]  = 32768
#define WS_S  32768    // S[B][DP]   = 512
#define WS_C  33280    // c[B]       = 64
#define WS_V  33344    // v[B][DK]   = 131584

// ===== MEASUREMENT ROUND: each kernel repeats its (idempotent) work REPS
// times so its dispatch exceeds the ~75us harness fills and shows up in the
// rocprof top-5 with full counters. Per-kernel time = row_dur / REPS. =====

// ---------------------------------------------------------------------------
// Kernel A (R3 shape): w[b,f] = gelu(text@Wt+bt)*Wa -> wT[f][b]; S[b].
// grid = 256 blocks: b = blk>>2, fg = blk&3 (128-f slice).
// ---------------------------------------------------------------------------
__global__ __launch_bounds__(256) void kA(
    const float* __restrict__ pos,   // [B][N][DP]
    const float* __restrict__ text,  // [B][N][DT]
    const float* __restrict__ Wt,    // [DT][DF]
    const float* __restrict__ bt,    // [DF]
    const float* __restrict__ Wa,    // [DF]
    float* __restrict__ wT,          // [DF][B]
    float* __restrict__ S,           // [B][DP]
    int reps)
{
    const int b = blockIdx.x >> 2;
    const int g = blockIdx.x & 3;
    const int t = threadIdx.x;
    const int a = t & 31;
    const int kh = t >> 5;

    __shared__ float tx[DT_];
    __shared__ float4 sred[8][32];
    __shared__ float spos[32][DP_];

    for (int rep = 0; rep < reps; ++rep) {
        for (int k = t; k < DT_; k += 256)
            tx[k] = text[(size_t)b * N_ * DT_ + k];

        if (g == 0) {
            const int d = t & 7, gi = t >> 3;
            float s = 0.f;
            for (int i = gi; i < N_; i += 32)
                s += pos[(size_t)b * N_ * DP_ + i * DP_ + d];
            spos[gi][d] = s;
        }
        __syncthreads();

        if (g == 0 && t < DP_) {
            float s = 0.f;
            #pragma unroll
            for (int gi = 0; gi < 32; ++gi) s += spos[gi][t];
            S[b * DP_ + t] = s;
        }

        const int f0 = g * 128 + 4 * a;
        float4 acc = make_float4(0.f, 0.f, 0.f, 0.f);
        const int kbase = kh * 96;
        for (int j = 0; j < 96; ++j) {
            const int k = kbase + j;
            const float x = tx[k];
            const float4 wv = *(const float4*)(Wt + (size_t)k * DF_ + f0);
            acc.x = fmaf(x, wv.x, acc.x);
            acc.y = fmaf(x, wv.y, acc.y);
            acc.z = fmaf(x, wv.z, acc.z);
            acc.w = fmaf(x, wv.w, acc.w);
        }
        sred[kh][a] = acc;
        __syncthreads();

        if (t < 32) {
            float4 s = sred[0][t];
            #pragma unroll
            for (int h = 1; h < 8; ++h) {
                const float4 p = sred[h][t];
                s.x += p.x; s.y += p.y; s.z += p.z; s.w += p.w;
            }
            const float sv[4] = {s.x, s.y, s.z, s.w};
            #pragma unroll
            for (int cc = 0; cc < 4; ++cc) {
                const int f = g * 128 + 4 * t + cc;
                const float z = sv[cc] + bt[f];
                const float ge = 0.5f * z * (1.f + erff(z * 0.70710678118654752f));
                wT[(size_t)f * B_ + b] = ge * Wa[f];
            }
        }
        __syncthreads();
        asm volatile("" ::: "memory");
    }
}

// ---------------------------------------------------------------------------
// Kernel B (R3 shape): v[b,k] = sum_f Wo[k,f]*w[b,f]. 514 main blocks x 4 rows,
// block 514: c[b].
// ---------------------------------------------------------------------------
__global__ __launch_bounds__(256) void kB(
    const float* __restrict__ Wo,    // [DK][DF]
    const float* __restrict__ bo,    // [DF]
    const float* __restrict__ ba,    // [1]
    const float* __restrict__ wT,    // [DF][B]
    float* __restrict__ v,           // [B][DK]
    float* __restrict__ c,           // [B]
    int reps)
{
    const int t = threadIdx.x;
    __shared__ float  wo[4][DF_];
    __shared__ float4 red[4][16][16];
    __shared__ float  sbo[DF_];
    __shared__ float4 cred[16][16];

    for (int rep = 0; rep < reps; ++rep) {
        if (blockIdx.x < 514) {
            const int k0 = blockIdx.x * 4;
            {
                const float4* src = (const float4*)(Wo + (size_t)k0 * DF_);
                float4*       dst = (float4*)wo;
                dst[t]       = src[t];
                dst[t + 256] = src[t + 256];
            }
            __syncthreads();

            const int bq = t & 15;
            const int fg = t >> 4;
            float4 acc0 = make_float4(0.f, 0.f, 0.f, 0.f);
            float4 acc1 = acc0, acc2 = acc0, acc3 = acc0;
            const int fbase = fg * 32;
            #pragma unroll 4
            for (int j = 0; j < 32; ++j) {
                const int f = fbase + j;
                const float4 wv = *(const float4*)(wT + (size_t)f * B_ + 4 * bq);
                const float s0 = wo[0][f], s1 = wo[1][f], s2 = wo[2][f], s3 = wo[3][f];
                acc0.x = fmaf(s0, wv.x, acc0.x); acc0.y = fmaf(s0, wv.y, acc0.y);
                acc0.z = fmaf(s0, wv.z, acc0.z); acc0.w = fmaf(s0, wv.w, acc0.w);
                acc1.x = fmaf(s1, wv.x, acc1.x); acc1.y = fmaf(s1, wv.y, acc1.y);
                acc1.z = fmaf(s1, wv.z, acc1.z); acc1.w = fmaf(s1, wv.w, acc1.w);
                acc2.x = fmaf(s2, wv.x, acc2.x); acc2.y = fmaf(s2, wv.y, acc2.y);
                acc2.z = fmaf(s2, wv.z, acc2.z); acc2.w = fmaf(s2, wv.w, acc2.w);
                acc3.x = fmaf(s3, wv.x, acc3.x); acc3.y = fmaf(s3, wv.y, acc3.y);
                acc3.z = fmaf(s3, wv.z, acc3.z); acc3.w = fmaf(s3, wv.w, acc3.w);
            }
            red[0][fg][bq] = acc0;
            red[1][fg][bq] = acc1;
            red[2][fg][bq] = acc2;
            red[3][fg][bq] = acc3;
            __syncthreads();
            if (t < 64) {
                const int r = t >> 4, bq2 = t & 15;
                float4 s = red[r][0][bq2];
                #pragma unroll
                for (int g = 1; g < 16; ++g) {
                    const float4 p = red[r][g][bq2];
                    s.x += p.x; s.y += p.y; s.z += p.z; s.w += p.w;
                }
                const float sv[4] = {s.x, s.y, s.z, s.w};
                #pragma unroll
                for (int cc = 0; cc < 4; ++cc)
                    v[(size_t)(4 * bq2 + cc) * DK_ + k0 + r] = sv[cc];
            }
            __syncthreads();
        } else {
            for (int k = t; k < DF_; k += 256) sbo[k] = bo[k];
            __syncthreads();
            const int bq = t & 15;
            const int fh = t >> 4;
            float4 acc = make_float4(0.f, 0.f, 0.f, 0.f);
            for (int j = 0; j < 32; ++j) {
                const int f = fh * 32 + j;
                const float s = sbo[f];
                const float4 wv = *(const float4*)(wT + (size_t)f * B_ + 4 * bq);
                acc.x = fmaf(s, wv.x, acc.x);
                acc.y = fmaf(s, wv.y, acc.y);
                acc.z = fmaf(s, wv.z, acc.z);
                acc.w = fmaf(s, wv.w, acc.w);
            }
            cred[fh][bq] = acc;
            __syncthreads();
            if (fh == 0) {
                float4 s = cred[0][bq];
                #pragma unroll
                for (int h = 1; h < 16; ++h) {
                    const float4 p = cred[h][bq];
                    s.x += p.x; s.y += p.y; s.z += p.z; s.w += p.w;
                }
                const float sv[4] = {s.x, s.y, s.z, s.w};
                #pragma unroll
                for (int cc = 0; cc < 4; ++cc)
                    c[4 * bq + cc] = sv[cc] + ba[0];
            }
            __syncthreads();
        }
        asm volatile("" ::: "memory");
    }
}

// ---------------------------------------------------------------------------
// Kernel C (R3 shape): 2 rows per wave, 2048 blocks (8/CU, 32 waves/CU).
// ---------------------------------------------------------------------------
__global__ __launch_bounds__(256) void kC(
    const float* __restrict__ visual, // [B][N][DV]
    const float* __restrict__ pos,    // [B][N][DP]
    const float* __restrict__ v,      // [B][DK]
    const float* __restrict__ S,      // [B][DP]
    const float* __restrict__ c,      // [B]
    float* __restrict__ out,          // [B][N]
    int reps)
{
    const int t    = threadIdx.x;
    const int wave = t >> 6;
    const int lane = t & 63;
    const int R0   = blockIdx.x * 8 + wave * 2;
    const int b    = R0 >> 8;
    const int i0   = R0 & 255;

    const float4* vb = (const float4*)(v + (size_t)b * DK_);
    const float4* v0 = (const float4*)(visual + ((size_t)b * N_ + i0) * DV_);

    for (int rep = 0; rep < reps; ++rep) {
        float a0 = 0.f, a1 = 0.f;
        #pragma unroll
        for (int j = 0; j < 8; ++j) {
            const int idx = lane + 64 * j;
            const float4 wv = vb[idx];
            const float4 x0 = v0[idx];
            const float4 x1 = v0[idx + 512];
            a0 = fmaf(x0.x, wv.x, a0); a0 = fmaf(x0.y, wv.y, a0);
            a0 = fmaf(x0.z, wv.z, a0); a0 = fmaf(x0.w, wv.w, a0);
            a1 = fmaf(x1.x, wv.x, a1); a1 = fmaf(x1.y, wv.y, a1);
            a1 = fmaf(x1.z, wv.z, a1); a1 = fmaf(x1.w, wv.w, a1);
        }
        #pragma unroll
        for (int off = 1; off < 64; off <<= 1) {
            a0 += __shfl_xor(a0, off, 64);
            a1 += __shfl_xor(a1, off, 64);
        }

        if (lane < 2) {
            const float accq = (lane == 0) ? a0 : a1;
            const int i = i0 + lane;
            const float* v2 = v + (size_t)b * DK_ + DV_;
            const float* pr = pos + ((size_t)b * N_ + i) * DP_;
            const float* Sb = S + b * DP_;
            float pd = 0.f, sd = 0.f;
            #pragma unroll
            for (int d = 0; d < DP_; ++d) {
                pd = fmaf(pr[d], v2[d], pd);
                sd = fmaf(Sb[d], v2[d], sd);
            }
            out[(size_t)b * N_ + i] = accq + 257.f * pd - sd + c[b];
        }
        asm volatile("" ::: "memory");
    }
}

// ---------------------------------------------------------------------------
extern "C" void kernel_launch(void* const* d_in, const int* in_sizes, int n_in,
                              void* d_out, int out_size, void* d_ws, size_t ws_size,
                              hipStream_t stream) {
    const float* visual   = (const float*)d_in[0];
    const float* position = (const float*)d_in[1];
    const float* text     = (const float*)d_in[2];
    const float* Wt       = (const float*)d_in[3];
    const float* bt       = (const float*)d_in[4];
    const float* Wo       = (const float*)d_in[5];
    const float* bo       = (const float*)d_in[6];
    const float* Wa       = (const float*)d_in[7];
    const float* ba       = (const float*)d_in[8];
    float* out = (float*)d_out;

    float* ws = (float*)d_ws;
    float* wT = ws + WS_WT;
    float* S  = ws + WS_S;
    float* c  = ws + WS_C;
    float* v  = ws + WS_V;

    kA<<<256, 256, 0, stream>>>(position, text, Wt, bt, Wa, wT, S, 32);
    kB<<<515, 256, 0, stream>>>(Wo, bo, ba, wT, v, c, 32);
    kC<<<2048, 256, 0, stream>>>(visual, position, v, S, c, out, 8);
}

// Round 7
// 59.943 us; speedup vs baseline: 9.1450x; 9.1450x over previous
//
#include <hip/hip_runtime.h>
#include <hip/hip_bf16.h>
#include <math.h>

// Problem constants
#define B_   64
#define N_   256
#define DV_  2048
#define DP_  8
#define DT_  768
#define DF_  512
#define DK_  2056   // DV + DP

// Workspace layout (floats):
#define WS_WT 0        // wT[DF][B]  = 32768
#define WS_S  32768    // S[B][DP]   = 512
#define WS_C  33280    // c[B]       = 64
#define WS_V  33344    // v[B][DK]   = 131584

// ---------------------------------------------------------------------------
// Kernel A: w[b,f] = gelu(text[b,0,:]@Wt+bt)[f]*Wa[f] -> wT[f][b]; S[b].
// grid = 256 blocks: bq = blk>>4 (16 b-quads), fg = blk&15 (16 groups of 32 f).
// Thread: fq = t&7 (f-quad), kc = t>>3 (32 chunks of 24 k) -> only 24
// float4 Wt loads per thread, unroll 8 keeps ~8 in flight (vs R3's 96
// serialized loads = 13.4 us latency chain).
// Reduce: butterfly over lane bits 3..5 (kc low bits), then 4-wave LDS reduce.
// ---------------------------------------------------------------------------
__global__ __launch_bounds__(256) void kA(
    const float* __restrict__ pos,   // [B][N][DP]
    const float* __restrict__ text,  // [B][N][DT]
    const float* __restrict__ Wt,    // [DT][DF]
    const float* __restrict__ bt,    // [DF]
    const float* __restrict__ Wa,    // [DF]
    float* __restrict__ wT,          // [DF][B]
    float* __restrict__ S)           // [B][DP]
{
    const int bq   = blockIdx.x >> 4;
    const int fg   = blockIdx.x & 15;
    const int t    = threadIdx.x;
    const int wave = t >> 6;
    const int lane = t & 63;

    __shared__ float  tx[4][DT_];     // 12 KB
    __shared__ float4 swA[4][8][4];   // 2 KB  [wave][fq][bb]
    __shared__ float  spos[4][4][DP_];

    // stage text[b,0,:] for 4 batches (768 float4)
    #pragma unroll
    for (int r = 0; r < 3; ++r) {
        const int idx = t + 256 * r;
        const int bb  = idx / 192;
        const int j   = idx - bb * 192;
        ((float4*)tx[bb])[j] =
            ((const float4*)text)[(size_t)(bq * 4 + bb) * (N_ * DT_ / 4) + j];
    }

    // position column sums (fg==0 blocks only)
    if (fg == 0 && t < 128) {
        const int bb = t >> 5, l = t & 31, d = l & 7, g4 = l >> 3;
        float s = 0.f;
        for (int i = g4; i < N_; i += 4)
            s += pos[(size_t)(bq * 4 + bb) * N_ * DP_ + i * DP_ + d];
        spos[bb][g4][d] = s;
    }
    __syncthreads();
    if (fg == 0 && t < 32) {
        const int bb = t >> 3, d = t & 7;
        S[(bq * 4 + bb) * DP_ + d] =
            spos[bb][0][d] + spos[bb][1][d] + spos[bb][2][d] + spos[bb][3][d];
    }

    // partial dot: 24 k's, 4 f's, 4 b's per thread
    const int fq = t & 7;
    const int kc = t >> 3;
    const int f0 = fg * 32 + fq * 4;
    float4 a0 = make_float4(0.f, 0.f, 0.f, 0.f);
    float4 a1 = a0, a2 = a0, a3 = a0;
    const int kbase = kc * 24;
    #pragma unroll 8
    for (int j = 0; j < 24; ++j) {
        const int k = kbase + j;
        const float4 wv = *(const float4*)(Wt + (size_t)k * DF_ + f0);
        const float x0 = tx[0][k], x1 = tx[1][k], x2 = tx[2][k], x3 = tx[3][k];
        a0.x = fmaf(x0, wv.x, a0.x); a0.y = fmaf(x0, wv.y, a0.y);
        a0.z = fmaf(x0, wv.z, a0.z); a0.w = fmaf(x0, wv.w, a0.w);
        a1.x = fmaf(x1, wv.x, a1.x); a1.y = fmaf(x1, wv.y, a1.y);
        a1.z = fmaf(x1, wv.z, a1.z); a1.w = fmaf(x1, wv.w, a1.w);
        a2.x = fmaf(x2, wv.x, a2.x); a2.y = fmaf(x2, wv.y, a2.y);
        a2.z = fmaf(x2, wv.z, a2.z); a2.w = fmaf(x2, wv.w, a2.w);
        a3.x = fmaf(x3, wv.x, a3.x); a3.y = fmaf(x3, wv.y, a3.y);
        a3.z = fmaf(x3, wv.z, a3.z); a3.w = fmaf(x3, wv.w, a3.w);
    }
    // butterfly all-reduce over kc-in-wave (lane bits 3,4,5)
    #pragma unroll
    for (int m = 8; m <= 32; m <<= 1) {
        a0.x += __shfl_xor(a0.x, m, 64); a0.y += __shfl_xor(a0.y, m, 64);
        a0.z += __shfl_xor(a0.z, m, 64); a0.w += __shfl_xor(a0.w, m, 64);
        a1.x += __shfl_xor(a1.x, m, 64); a1.y += __shfl_xor(a1.y, m, 64);
        a1.z += __shfl_xor(a1.z, m, 64); a1.w += __shfl_xor(a1.w, m, 64);
        a2.x += __shfl_xor(a2.x, m, 64); a2.y += __shfl_xor(a2.y, m, 64);
        a2.z += __shfl_xor(a2.z, m, 64); a2.w += __shfl_xor(a2.w, m, 64);
        a3.x += __shfl_xor(a3.x, m, 64); a3.y += __shfl_xor(a3.y, m, 64);
        a3.z += __shfl_xor(a3.z, m, 64); a3.w += __shfl_xor(a3.w, m, 64);
    }
    if (lane < 8) {   // lane == fq
        swA[wave][lane][0] = a0;
        swA[wave][lane][1] = a1;
        swA[wave][lane][2] = a2;
        swA[wave][lane][3] = a3;
    }
    __syncthreads();

    if (t < 32) {
        const int bb = t >> 3, fq2 = t & 7;
        float4 s = swA[0][fq2][bb];
        #pragma unroll
        for (int w = 1; w < 4; ++w) {
            const float4 p = swA[w][fq2][bb];
            s.x += p.x; s.y += p.y; s.z += p.z; s.w += p.w;
        }
        const float sv[4] = {s.x, s.y, s.z, s.w};
        const int b = bq * 4 + bb;
        #pragma unroll
        for (int cc = 0; cc < 4; ++cc) {
            const int f = fg * 32 + fq2 * 4 + cc;
            const float z = sv[cc] + bt[f];
            const float ge = 0.5f * z * (1.f + erff(z * 0.70710678118654752f));
            wT[(size_t)f * B_ + b] = ge * Wa[f];
        }
    }
}

// ---------------------------------------------------------------------------
// Kernel B (R3 shape, ~1.5us measured): v[b,k] = sum_f Wo[k,f]*w[b,f].
// Blocks 0..513: 4 k-rows each; block 514: c[b].
// ---------------------------------------------------------------------------
__global__ __launch_bounds__(256) void kB(
    const float* __restrict__ Wo,    // [DK][DF]
    const float* __restrict__ bo,    // [DF]
    const float* __restrict__ ba,    // [1]
    const float* __restrict__ wT,    // [DF][B]
    float* __restrict__ v,           // [B][DK]
    float* __restrict__ c)           // [B]
{
    const int t = threadIdx.x;
    __shared__ float  wo[4][DF_];
    __shared__ float4 red[4][16][16];
    __shared__ float  sbo[DF_];
    __shared__ float4 cred[16][16];

    if (blockIdx.x < 514) {
        const int k0 = blockIdx.x * 4;
        {
            const float4* src = (const float4*)(Wo + (size_t)k0 * DF_);
            float4*       dst = (float4*)wo;
            dst[t]       = src[t];
            dst[t + 256] = src[t + 256];
        }
        __syncthreads();

        const int bq = t & 15;
        const int fg = t >> 4;
        float4 acc0 = make_float4(0.f, 0.f, 0.f, 0.f);
        float4 acc1 = acc0, acc2 = acc0, acc3 = acc0;
        const int fbase = fg * 32;
        #pragma unroll 4
        for (int j = 0; j < 32; ++j) {
            const int f = fbase + j;
            const float4 wv = *(const float4*)(wT + (size_t)f * B_ + 4 * bq);
            const float s0 = wo[0][f], s1 = wo[1][f], s2 = wo[2][f], s3 = wo[3][f];
            acc0.x = fmaf(s0, wv.x, acc0.x); acc0.y = fmaf(s0, wv.y, acc0.y);
            acc0.z = fmaf(s0, wv.z, acc0.z); acc0.w = fmaf(s0, wv.w, acc0.w);
            acc1.x = fmaf(s1, wv.x, acc1.x); acc1.y = fmaf(s1, wv.y, acc1.y);
            acc1.z = fmaf(s1, wv.z, acc1.z); acc1.w = fmaf(s1, wv.w, acc1.w);
            acc2.x = fmaf(s2, wv.x, acc2.x); acc2.y = fmaf(s2, wv.y, acc2.y);
            acc2.z = fmaf(s2, wv.z, acc2.z); acc2.w = fmaf(s2, wv.w, acc2.w);
            acc3.x = fmaf(s3, wv.x, acc3.x); acc3.y = fmaf(s3, wv.y, acc3.y);
            acc3.z = fmaf(s3, wv.z, acc3.z); acc3.w = fmaf(s3, wv.w, acc3.w);
        }
        red[0][fg][bq] = acc0;
        red[1][fg][bq] = acc1;
        red[2][fg][bq] = acc2;
        red[3][fg][bq] = acc3;
        __syncthreads();
        if (t < 64) {
            const int r = t >> 4, bq2 = t & 15;
            float4 s = red[r][0][bq2];
            #pragma unroll
            for (int g = 1; g < 16; ++g) {
                const float4 p = red[r][g][bq2];
                s.x += p.x; s.y += p.y; s.z += p.z; s.w += p.w;
            }
            const float sv[4] = {s.x, s.y, s.z, s.w};
            #pragma unroll
            for (int cc = 0; cc < 4; ++cc)
                v[(size_t)(4 * bq2 + cc) * DK_ + k0 + r] = sv[cc];
        }
    } else {
        for (int k = t; k < DF_; k += 256) sbo[k] = bo[k];
        __syncthreads();
        const int bq = t & 15;
        const int fh = t >> 4;
        float4 acc = make_float4(0.f, 0.f, 0.f, 0.f);
        for (int j = 0; j < 32; ++j) {
            const int f = fh * 32 + j;
            const float s = sbo[f];
            const float4 wv = *(const float4*)(wT + (size_t)f * B_ + 4 * bq);
            acc.x = fmaf(s, wv.x, acc.x);
            acc.y = fmaf(s, wv.y, acc.y);
            acc.z = fmaf(s, wv.z, acc.z);
            acc.w = fmaf(s, wv.w, acc.w);
        }
        cred[fh][bq] = acc;
        __syncthreads();
        if (fh == 0) {
            float4 s = cred[0][bq];
            #pragma unroll
            for (int h = 1; h < 16; ++h) {
                const float4 p = cred[h][bq];
                s.x += p.x; s.y += p.y; s.z += p.z; s.w += p.w;
            }
            const float sv[4] = {s.x, s.y, s.z, s.w};
            #pragma unroll
            for (int cc = 0; cc < 4; ++cc)
                c[4 * bq + cc] = sv[cc] + ba[0];
        }
    }
}

// ---------------------------------------------------------------------------
// Kernel C (R3 shape, ~8us measured = L3-BW floor): 2 rows per wave,
// 2048 blocks (8/CU, 32 waves/CU).
// ---------------------------------------------------------------------------
__global__ __launch_bounds__(256) void kC(
    const float* __restrict__ visual, // [B][N][DV]
    const float* __restrict__ pos,    // [B][N][DP]
    const float* __restrict__ v,      // [B][DK]
    const float* __restrict__ S,      // [B][DP]
    const float* __restrict__ c,      // [B]
    float* __restrict__ out)          // [B][N]
{
    const int t    = threadIdx.x;
    const int wave = t >> 6;
    const int lane = t & 63;
    const int R0   = blockIdx.x * 8 + wave * 2;
    const int b    = R0 >> 8;
    const int i0   = R0 & 255;

    const float4* vb = (const float4*)(v + (size_t)b * DK_);
    const float4* v0 = (const float4*)(visual + ((size_t)b * N_ + i0) * DV_);

    float a0 = 0.f, a1 = 0.f;
    #pragma unroll
    for (int j = 0; j < 8; ++j) {
        const int idx = lane + 64 * j;
        const float4 wv = vb[idx];
        const float4 x0 = v0[idx];
        const float4 x1 = v0[idx + 512];
        a0 = fmaf(x0.x, wv.x, a0); a0 = fmaf(x0.y, wv.y, a0);
        a0 = fmaf(x0.z, wv.z, a0); a0 = fmaf(x0.w, wv.w, a0);
        a1 = fmaf(x1.x, wv.x, a1); a1 = fmaf(x1.y, wv.y, a1);
        a1 = fmaf(x1.z, wv.z, a1); a1 = fmaf(x1.w, wv.w, a1);
    }
    #pragma unroll
    for (int off = 1; off < 64; off <<= 1) {
        a0 += __shfl_xor(a0, off, 64);
        a1 += __shfl_xor(a1, off, 64);
    }

    if (lane < 2) {
        const float accq = (lane == 0) ? a0 : a1;
        const int i = i0 + lane;
        const float* v2 = v + (size_t)b * DK_ + DV_;
        const float* pr = pos + ((size_t)b * N_ + i) * DP_;
        const float* Sb = S + b * DP_;
        float pd = 0.f, sd = 0.f;
        #pragma unroll
        for (int d = 0; d < DP_; ++d) {
            pd = fmaf(pr[d], v2[d], pd);
            sd = fmaf(Sb[d], v2[d], sd);
        }
        out[(size_t)b * N_ + i] = accq + 257.f * pd - sd + c[b];
    }
}

// ---------------------------------------------------------------------------
extern "C" void kernel_launch(void* const* d_in, const int* in_sizes, int n_in,
                              void* d_out, int out_size, void* d_ws, size_t ws_size,
                              hipStream_t stream) {
    const float* visual   = (const float*)d_in[0];
    const float* position = (const float*)d_in[1];
    const float* text     = (const float*)d_in[2];
    const float* Wt       = (const float*)d_in[3];
    const float* bt       = (const float*)d_in[4];
    const float* Wo       = (const float*)d_in[5];
    const float* bo       = (const float*)d_in[6];
    const float* Wa       = (const float*)d_in[7];
    const float* ba       = (const float*)d_in[8];
    float* out = (float*)d_out;

    float* ws = (float*)d_ws;
    float* wT = ws + WS_WT;
    float* S  = ws + WS_S;
    float* c  = ws + WS_C;
    float* v  = ws + WS_V;

    kA<<<256, 256, 0, stream>>>(position, text, Wt, bt, Wa, wT, S);
    kB<<<515, 256, 0, stream>>>(Wo, bo, ba, wT, v, c);
    kC<<<2048, 256, 0, stream>>>(visual, position, v, S, c, out);
}

// Round 8
// 59.942 us; speedup vs baseline: 9.1451x; 1.0000x over previous
//
#include <hip/hip_runtime.h>
#include <hip/hip_bf16.h>
#include <math.h>

// Problem constants
#define B_   64
#define N_   256
#define DV_  2048
#define DP_  8
#define DT_  768
#define DF_  512
#define DK_  2056   // DV + DP

// Workspace layout (floats):
#define WS_WT 0        // wT[DF][B]  = 32768
#define WS_S  32768    // S[B][DP]   = 512
#define WS_C  33280    // c[B]       = 64
#define WS_V  33344    // v[B][DK]   = 131584

// ---------------------------------------------------------------------------
// Kernel A (~2us): w[b,f] = gelu(text[b,0,:]@Wt+bt)[f]*Wa[f] -> wT[f][b]; S[b].
// grid = 256 blocks: bq = blk>>4 (16 b-quads), fg = blk&15 (16 groups of 32 f).
// Thread: fq = t&7 (f-quad), kc = t>>3 (32 chunks of 24 k) -> 24 float4 Wt
// loads per thread, unroll 8 keeps ~8 in flight.
// ---------------------------------------------------------------------------
__global__ __launch_bounds__(256) void kA(
    const float* __restrict__ pos,   // [B][N][DP]
    const float* __restrict__ text,  // [B][N][DT]
    const float* __restrict__ Wt,    // [DT][DF]
    const float* __restrict__ bt,    // [DF]
    const float* __restrict__ Wa,    // [DF]
    float* __restrict__ wT,          // [DF][B]
    float* __restrict__ S)           // [B][DP]
{
    const int bq   = blockIdx.x >> 4;
    const int fg   = blockIdx.x & 15;
    const int t    = threadIdx.x;
    const int wave = t >> 6;
    const int lane = t & 63;

    __shared__ float  tx[4][DT_];     // 12 KB
    __shared__ float4 swA[4][8][4];   // 2 KB  [wave][fq][bb]
    __shared__ float  spos[4][4][DP_];

    // stage text[b,0,:] for 4 batches: 768 float4, thread t handles
    // bb = t>>6 (wave), j = lane + 64*r  (192 float4 per bb, r=0..2)
    {
        const float4* src = (const float4*)text + (size_t)(bq * 4 + wave) * (N_ * DT_ / 4);
        float4* dst = (float4*)tx[wave];
        #pragma unroll
        for (int r = 0; r < 3; ++r)
            dst[lane + 64 * r] = src[lane + 64 * r];
    }

    // position column sums (fg==0 blocks only)
    if (fg == 0 && t < 128) {
        const int bb = t >> 5, l = t & 31, d = l & 7, g4 = l >> 3;
        float s = 0.f;
        for (int i = g4; i < N_; i += 4)
            s += pos[(size_t)(bq * 4 + bb) * N_ * DP_ + i * DP_ + d];
        spos[bb][g4][d] = s;
    }
    __syncthreads();
    if (fg == 0 && t < 32) {
        const int bb = t >> 3, d = t & 7;
        S[(bq * 4 + bb) * DP_ + d] =
            spos[bb][0][d] + spos[bb][1][d] + spos[bb][2][d] + spos[bb][3][d];
    }

    // partial dot: 24 k's, 4 f's, 4 b's per thread
    const int fq = t & 7;
    const int kc = t >> 3;
    const int f0 = fg * 32 + fq * 4;
    float4 a0 = make_float4(0.f, 0.f, 0.f, 0.f);
    float4 a1 = a0, a2 = a0, a3 = a0;
    const int kbase = kc * 24;
    #pragma unroll 8
    for (int j = 0; j < 24; ++j) {
        const int k = kbase + j;
        const float4 wv = *(const float4*)(Wt + (size_t)k * DF_ + f0);
        const float x0 = tx[0][k], x1 = tx[1][k], x2 = tx[2][k], x3 = tx[3][k];
        a0.x = fmaf(x0, wv.x, a0.x); a0.y = fmaf(x0, wv.y, a0.y);
        a0.z = fmaf(x0, wv.z, a0.z); a0.w = fmaf(x0, wv.w, a0.w);
        a1.x = fmaf(x1, wv.x, a1.x); a1.y = fmaf(x1, wv.y, a1.y);
        a1.z = fmaf(x1, wv.z, a1.z); a1.w = fmaf(x1, wv.w, a1.w);
        a2.x = fmaf(x2, wv.x, a2.x); a2.y = fmaf(x2, wv.y, a2.y);
        a2.z = fmaf(x2, wv.z, a2.z); a2.w = fmaf(x2, wv.w, a2.w);
        a3.x = fmaf(x3, wv.x, a3.x); a3.y = fmaf(x3, wv.y, a3.y);
        a3.z = fmaf(x3, wv.z, a3.z); a3.w = fmaf(x3, wv.w, a3.w);
    }
    // butterfly all-reduce over kc-in-wave (lane bits 3,4,5)
    #pragma unroll
    for (int m = 8; m <= 32; m <<= 1) {
        a0.x += __shfl_xor(a0.x, m, 64); a0.y += __shfl_xor(a0.y, m, 64);
        a0.z += __shfl_xor(a0.z, m, 64); a0.w += __shfl_xor(a0.w, m, 64);
        a1.x += __shfl_xor(a1.x, m, 64); a1.y += __shfl_xor(a1.y, m, 64);
        a1.z += __shfl_xor(a1.z, m, 64); a1.w += __shfl_xor(a1.w, m, 64);
        a2.x += __shfl_xor(a2.x, m, 64); a2.y += __shfl_xor(a2.y, m, 64);
        a2.z += __shfl_xor(a2.z, m, 64); a2.w += __shfl_xor(a2.w, m, 64);
        a3.x += __shfl_xor(a3.x, m, 64); a3.y += __shfl_xor(a3.y, m, 64);
        a3.z += __shfl_xor(a3.z, m, 64); a3.w += __shfl_xor(a3.w, m, 64);
    }
    if (lane < 8) {   // lane == fq
        swA[wave][lane][0] = a0;
        swA[wave][lane][1] = a1;
        swA[wave][lane][2] = a2;
        swA[wave][lane][3] = a3;
    }
    __syncthreads();

    if (t < 32) {
        const int bb = t >> 3, fq2 = t & 7;
        float4 s = swA[0][fq2][bb];
        #pragma unroll
        for (int w = 1; w < 4; ++w) {
            const float4 p = swA[w][fq2][bb];
            s.x += p.x; s.y += p.y; s.z += p.z; s.w += p.w;
        }
        const float sv[4] = {s.x, s.y, s.z, s.w};
        const int b = bq * 4 + bb;
        #pragma unroll
        for (int cc = 0; cc < 4; ++cc) {
            const int f = fg * 32 + fq2 * 4 + cc;
            const float z = sv[cc] + bt[f];
            const float ge = 0.5f * z * (1.f + erff(z * 0.70710678118654752f));
            wT[(size_t)f * B_ + b] = ge * Wa[f];
        }
    }
}

// ---------------------------------------------------------------------------
// Kernel B (~1.5us measured): v[b,k] = sum_f Wo[k,f]*w[b,f].
// Blocks 0..513: 4 k-rows each; block 514: c[b].
// ---------------------------------------------------------------------------
__global__ __launch_bounds__(256) void kB(
    const float* __restrict__ Wo,    // [DK][DF]
    const float* __restrict__ bo,    // [DF]
    const float* __restrict__ ba,    // [1]
    const float* __restrict__ wT,    // [DF][B]
    float* __restrict__ v,           // [B][DK]
    float* __restrict__ c)           // [B]
{
    const int t = threadIdx.x;
    __shared__ float  wo[4][DF_];
    __shared__ float4 red[4][16][16];
    __shared__ float  sbo[DF_];
    __shared__ float4 cred[16][16];

    if (blockIdx.x < 514) {
        const int k0 = blockIdx.x * 4;
        {
            const float4* src = (const float4*)(Wo + (size_t)k0 * DF_);
            float4*       dst = (float4*)wo;
            dst[t]       = src[t];
            dst[t + 256] = src[t + 256];
        }
        __syncthreads();

        const int bq = t & 15;
        const int fg = t >> 4;
        float4 acc0 = make_float4(0.f, 0.f, 0.f, 0.f);
        float4 acc1 = acc0, acc2 = acc0, acc3 = acc0;
        const int fbase = fg * 32;
        #pragma unroll 4
        for (int j = 0; j < 32; ++j) {
            const int f = fbase + j;
            const float4 wv = *(const float4*)(wT + (size_t)f * B_ + 4 * bq);
            const float s0 = wo[0][f], s1 = wo[1][f], s2 = wo[2][f], s3 = wo[3][f];
            acc0.x = fmaf(s0, wv.x, acc0.x); acc0.y = fmaf(s0, wv.y, acc0.y);
            acc0.z = fmaf(s0, wv.z, acc0.z); acc0.w = fmaf(s0, wv.w, acc0.w);
            acc1.x = fmaf(s1, wv.x, acc1.x); acc1.y = fmaf(s1, wv.y, acc1.y);
            acc1.z = fmaf(s1, wv.z, acc1.z); acc1.w = fmaf(s1, wv.w, acc1.w);
            acc2.x = fmaf(s2, wv.x, acc2.x); acc2.y = fmaf(s2, wv.y, acc2.y);
            acc2.z = fmaf(s2, wv.z, acc2.z); acc2.w = fmaf(s2, wv.w, acc2.w);
            acc3.x = fmaf(s3, wv.x, acc3.x); acc3.y = fmaf(s3, wv.y, acc3.y);
            acc3.z = fmaf(s3, wv.z, acc3.z); acc3.w = fmaf(s3, wv.w, acc3.w);
        }
        red[0][fg][bq] = acc0;
        red[1][fg][bq] = acc1;
        red[2][fg][bq] = acc2;
        red[3][fg][bq] = acc3;
        __syncthreads();
        if (t < 64) {
            const int r = t >> 4, bq2 = t & 15;
            float4 s = red[r][0][bq2];
            #pragma unroll
            for (int g = 1; g < 16; ++g) {
                const float4 p = red[r][g][bq2];
                s.x += p.x; s.y += p.y; s.z += p.z; s.w += p.w;
            }
            const float sv[4] = {s.x, s.y, s.z, s.w};
            #pragma unroll
            for (int cc = 0; cc < 4; ++cc)
                v[(size_t)(4 * bq2 + cc) * DK_ + k0 + r] = sv[cc];
        }
    } else {
        for (int k = t; k < DF_; k += 256) sbo[k] = bo[k];
        __syncthreads();
        const int bq = t & 15;
        const int fh = t >> 4;
        float4 acc = make_float4(0.f, 0.f, 0.f, 0.f);
        for (int j = 0; j < 32; ++j) {
            const int f = fh * 32 + j;
            const float s = sbo[f];
            const float4 wv = *(const float4*)(wT + (size_t)f * B_ + 4 * bq);
            acc.x = fmaf(s, wv.x, acc.x);
            acc.y = fmaf(s, wv.y, acc.y);
            acc.z = fmaf(s, wv.z, acc.z);
            acc.w = fmaf(s, wv.w, acc.w);
        }
        cred[fh][bq] = acc;
        __syncthreads();
        if (fh == 0) {
            float4 s = cred[0][bq];
            #pragma unroll
            for (int h = 1; h < 16; ++h) {
                const float4 p = cred[h][bq];
                s.x += p.x; s.y += p.y; s.z += p.z; s.w += p.w;
            }
            const float sv[4] = {s.x, s.y, s.z, s.w};
            #pragma unroll
            for (int cc = 0; cc < 4; ++cc)
                c[4 * bq + cc] = sv[cc] + ba[0];
        }
    }
}

// ---------------------------------------------------------------------------
// Kernel C (~8us measured = L3-BW floor): 2 rows per wave, 2048 blocks
// (8/CU, 32 waves/CU).
// out[b,i] = visual[b,i,:].v1[b] + 257*pos[b,i,:].v2[b] - S[b].v2[b] + c[b]
// ---------------------------------------------------------------------------
__global__ __launch_bounds__(256) void kC(
    const float* __restrict__ visual, // [B][N][DV]
    const float* __restrict__ pos,    // [B][N][DP]
    const float* __restrict__ v,      // [B][DK]
    const float* __restrict__ S,      // [B][DP]
    const float* __restrict__ c,      // [B]
    float* __restrict__ out)          // [B][N]
{
    const int t    = threadIdx.x;
    const int wave = t >> 6;
    const int lane = t & 63;
    const int R0   = blockIdx.x * 8 + wave * 2;
    const int b    = R0 >> 8;
    const int i0   = R0 & 255;

    const float4* vb = (const float4*)(v + (size_t)b * DK_);
    const float4* v0 = (const float4*)(visual + ((size_t)b * N_ + i0) * DV_);

    float a0 = 0.f, a1 = 0.f;
    #pragma unroll
    for (int j = 0; j < 8; ++j) {
        const int idx = lane + 64 * j;
        const float4 wv = vb[idx];
        const float4 x0 = v0[idx];
        const float4 x1 = v0[idx + 512];
        a0 = fmaf(x0.x, wv.x, a0); a0 = fmaf(x0.y, wv.y, a0);
        a0 = fmaf(x0.z, wv.z, a0); a0 = fmaf(x0.w, wv.w, a0);
        a1 = fmaf(x1.x, wv.x, a1); a1 = fmaf(x1.y, wv.y, a1);
        a1 = fmaf(x1.z, wv.z, a1); a1 = fmaf(x1.w, wv.w, a1);
    }
    #pragma unroll
    for (int off = 1; off < 64; off <<= 1) {
        a0 += __shfl_xor(a0, off, 64);
        a1 += __shfl_xor(a1, off, 64);
    }

    if (lane < 2) {
        const float accq = (lane == 0) ? a0 : a1;
        const int i = i0 + lane;
        const float* v2 = v + (size_t)b * DK_ + DV_;
        const float* pr = pos + ((size_t)b * N_ + i) * DP_;
        const float* Sb = S + b * DP_;
        float pd = 0.f, sd = 0.f;
        #pragma unroll
        for (int d = 0; d < DP_; ++d) {
            pd = fmaf(pr[d], v2[d], pd);
            sd = fmaf(Sb[d], v2[d], sd);
        }
        out[(size_t)b * N_ + i] = accq + 257.f * pd - sd + c[b];
    }
}

// ---------------------------------------------------------------------------
extern "C" void kernel_launch(void* const* d_in, const int* in_sizes, int n_in,
                              void* d_out, int out_size, void* d_ws, size_t ws_size,
                              hipStream_t stream) {
    const float* visual   = (const float*)d_in[0];
    const float* position = (const float*)d_in[1];
    const float* text     = (const float*)d_in[2];
    const float* Wt       = (const float*)d_in[3];
    const float* bt       = (const float*)d_in[4];
    const float* Wo       = (const float*)d_in[5];
    const float* bo       = (const float*)d_in[6];
    const float* Wa       = (const float*)d_in[7];
    const float* ba       = (const float*)d_in[8];
    float* out = (float*)d_out;

    float* ws = (float*)d_ws;
    float* wT = ws + WS_WT;
    float* S  = ws + WS_S;
    float* c  = ws + WS_C;
    float* v  = ws + WS_V;

    kA<<<256, 256, 0, stream>>>(position, text, Wt, bt, Wa, wT, S);
    kB<<<515, 256, 0, stream>>>(Wo, bo, ba, wT, v, c);
    kC<<<2048, 256, 0, stream>>>(visual, position, v, S, c, out);
}